// Round 4
// baseline (279.301 us; speedup 1.0000x reference)
//
#include <hip/hip_runtime.h>

// Problem constants: B=4, C=3, H=512, W=960, K2=16 -> K=4
#define BB 4
#define CC 3
#define HH 512
#define WW 960
#define HW (HH * WW)
#define NQ (BB * HW / 4)   // pixel quads: 491520 = 1920 * 256

typedef float f4 __attribute__((ext_vector_type(4)));

__global__ __launch_bounds__(256, 2)
void filter_interp_quad(const float* __restrict__ inp,
                        const float* __restrict__ flow,
                        const float* __restrict__ filt,
                        float* __restrict__ out) {
    const int t = blockIdx.x * 256 + threadIdx.x;
    const int qpb = HW / 4;                 // quads per batch image
    const int b   = t / qpb;
    const int q   = t - b * qpb;
    const int y   = q / (WW / 4);
    const int x0  = (q - y * (WW / 4)) * 4; // first pixel of this thread's quad
    const int rem = y * WW + x0;            // flat pixel offset (16B aligned)

    // ---- Vectorized uniform loads: flow (2x f4), filter taps (16x f4) ----
    const f4 fx4 = *(const f4*)(flow + (size_t)(b * 2 + 0) * HW + rem);
    const f4 fy4 = *(const f4*)(flow + (size_t)(b * 2 + 1) * HW + rem);

    f4 ft[16];
    const float* fb = filt + (size_t)b * 16 * HW + rem;
#pragma unroll
    for (int k = 0; k < 16; ++k) ft[k] = *(const f4*)(fb + (size_t)k * HW);

    const float* ib = inp + (size_t)b * CC * HW;

    f4 accv[CC];
#pragma unroll
    for (int c = 0; c < CC; ++c) accv[c] = (f4){0.f, 0.f, 0.f, 0.f};

#pragma unroll
    for (int p = 0; p < 4; ++p) {
        const float fx = fx4[p];
        const float fy = fy4[p];
        const int   xp = x0 + p;
        const float x2 = (float)xp + fx;
        const float y2 = (float)y + fy;

        const bool valid = (x2 >= 0.0f) && (x2 <= (float)(WW - 1)) &&
                           (y2 >= 0.0f) && (y2 <= (float)(HH - 1)) &&
                           (fabsf(fx) < (float)WW * 0.5f) &&
                           (fabsf(fy) < (float)HH * 0.5f);
        if (!valid) continue;  // accv lanes stay 0

        const int ix = (int)floorf(x2);
        const int iy = (int)floorf(y2);
        const float alpha = x2 - (float)ix;
        const float beta  = y2 - (float)iy;

        const float wTL = (1.0f - alpha) * (1.0f - beta);
        const float wTR = alpha * (1.0f - beta);
        const float wBL = (1.0f - alpha) * beta;
        const float wBR = alpha * beta;

        // Fold 16 taps x 4 bilinear weights into a 5x5 weight map.
        float Wm[5][5];
#pragma unroll
        for (int j = 0; j < 5; ++j)
#pragma unroll
            for (int i = 0; i < 5; ++i) Wm[j][i] = 0.0f;
#pragma unroll
        for (int dj = 0; dj < 4; ++dj) {
#pragma unroll
            for (int di = 0; di < 4; ++di) {
                const float f = ft[dj * 4 + di][p];
                Wm[dj][di]         += f * wTL;
                Wm[dj][di + 1]     += f * wTR;
                Wm[dj + 1][di]     += f * wBL;
                Wm[dj + 1][di + 1] += f * wBR;
            }
        }

        const int ixL0 = ix - 1;
        const int iyT0 = iy - 1;
        int R[5];
#pragma unroll
        for (int j = 0; j < 5; ++j) R[j] = min(max(iyT0 + j, 0), HH - 1);

        float a0c = 0.f, a1c = 0.f, a2c = 0.f;

        if (ixL0 >= 0 && ixL0 + 4 <= WW - 1) {
            // Fast path: aligned 8-float window + barrel-shifted weights.
            const int a0 = ixL0 & ~3;
            const int o  = ixL0 - a0;
            const bool s2 = (o & 2) != 0;
            const bool s1 = (o & 1) != 0;
            float We[5][8];
#pragma unroll
            for (int j = 0; j < 5; ++j) {
                float tt[8];
#pragma unroll
                for (int i = 0; i < 8; ++i) tt[i] = (i < 5) ? Wm[j][i] : 0.0f;
                float u[8];
#pragma unroll
                for (int i = 0; i < 8; ++i)
                    u[i] = s2 ? ((i >= 2) ? tt[i - 2] : 0.0f) : tt[i];
#pragma unroll
                for (int i = 0; i < 8; ++i)
                    We[j][i] = s1 ? ((i >= 1) ? u[i - 1] : 0.0f) : u[i];
            }

#pragma unroll
            for (int j = 0; j < 5; ++j) {
                const size_t rowoff = (size_t)R[j] * WW + a0;
                const float* r0p = ib + rowoff;                 // c = 0
                const float* r1p = r0p + HW;                    // c = 1
                const float* r2p = r1p + HW;                    // c = 2
                const f4 q00 = *(const f4*)(r0p);
                const f4 q01 = *(const f4*)(r0p + 4);
                const f4 q10 = *(const f4*)(r1p);
                const f4 q11 = *(const f4*)(r1p + 4);
                const f4 q20 = *(const f4*)(r2p);
                const f4 q21 = *(const f4*)(r2p + 4);
#pragma unroll
                for (int i = 0; i < 4; ++i) {
                    a0c += q00[i] * We[j][i];
                    a0c += q01[i] * We[j][i + 4];
                    a1c += q10[i] * We[j][i];
                    a1c += q11[i] * We[j][i + 4];
                    a2c += q20[i] * We[j][i];
                    a2c += q21[i] * We[j][i + 4];
                }
            }
        } else {
            // Rare slow path: clamped scalar gathers (verified R1 logic).
            int S[5];
#pragma unroll
            for (int i = 0; i < 5; ++i) S[i] = min(max(ixL0 + i, 0), WW - 1);
            float* accp[3] = {&a0c, &a1c, &a2c};
#pragma unroll
            for (int c = 0; c < CC; ++c) {
                const float* ic = ib + (size_t)c * HW;
                float a = 0.0f;
#pragma unroll
                for (int j = 0; j < 5; ++j) {
                    const float* row = ic + (size_t)R[j] * WW;
#pragma unroll
                    for (int i = 0; i < 5; ++i) a += row[S[i]] * Wm[j][i];
                }
                *accp[c] = a;
            }
        }

        accv[0][p] = a0c;
        accv[1][p] = a1c;
        accv[2][p] = a2c;
    }

    // ---- Vectorized stores: 3x dwordx4 ----
    float* ob = out + (size_t)b * CC * HW + rem;
    *(f4*)(ob)          = accv[0];
    *(f4*)(ob + HW)     = accv[1];
    *(f4*)(ob + 2 * HW) = accv[2];
}

extern "C" void kernel_launch(void* const* d_in, const int* in_sizes, int n_in,
                              void* d_out, int out_size, void* d_ws, size_t ws_size,
                              hipStream_t stream) {
    const float* teninput  = (const float*)d_in[0];
    const float* tenflow   = (const float*)d_in[1];
    const float* tenfilter = (const float*)d_in[2];
    float* out = (float*)d_out;

    const int blocks = NQ / 256;  // 1920
    filter_interp_quad<<<blocks, 256, 0, stream>>>(teninput, tenflow, tenfilter, out);
}

// Round 5
// 242.998 us; speedup vs baseline: 1.1494x; 1.1494x over previous
//
#include <hip/hip_runtime.h>

// Problem constants: B=4, C=3, H=512, W=960, K2=16 -> K=4
#define BB 4
#define CC 3
#define HH 512
#define WW 960
#define HW (HH * WW)

typedef float f4 __attribute__((ext_vector_type(4)));

__global__ __launch_bounds__(256)
void filter_interp_batch(const float* __restrict__ inp,
                         const float* __restrict__ flow,
                         const float* __restrict__ filt,
                         float* __restrict__ out) {
    const int bpi = HW / 256;             // blocks per image: 1920
    const int b   = blockIdx.x / bpi;     // block-uniform -> scalar bases
    const int rem = (blockIdx.x - b * bpi) * 256 + threadIdx.x;
    const int y   = rem / WW;
    const int x   = rem - y * WW;

    // ---- Issue flow loads first (head of the critical path) ----
    const float* flb = flow + (size_t)(b * 2) * HW;
    const float fx = flb[rem];
    const float fy = flb[rem + HW];

    // ---- Issue all 16 filter loads (independent of flow) ----
    float ftv[16];
    const float* fb = filt + (size_t)(b * 16) * HW + rem;
#pragma unroll
    for (int k = 0; k < 16; ++k) ftv[k] = fb[(size_t)k * HW];

    // ---- Flow math (waits only on the 2 flow loads) ----
    const float x2 = (float)x + fx;
    const float y2 = (float)y + fy;
    const bool valid = (x2 >= 0.0f) && (x2 <= (float)(WW - 1)) &&
                       (y2 >= 0.0f) && (y2 <= (float)(HH - 1)) &&
                       (fabsf(fx) < (float)WW * 0.5f) &&
                       (fabsf(fy) < (float)HH * 0.5f);

    const float fxf = floorf(x2);
    const float fyf = floorf(y2);
    // Sanitize per-lane state for invalid lanes (branchless; avoids NaN and
    // keeps them on the fast path with in-range addresses; weights become 0).
    const float alpha = valid ? (x2 - fxf) : 0.0f;
    const float beta  = valid ? (y2 - fyf) : 0.0f;
    const int   ix    = valid ? (int)fxf : 480;
    const int   iy    = valid ? (int)fyf : 256;
    const float vf    = valid ? 1.0f : 0.0f;

    const float wTL = vf * (1.0f - alpha) * (1.0f - beta);
    const float wTR = vf * alpha * (1.0f - beta);
    const float wBL = vf * (1.0f - alpha) * beta;
    const float wBR = vf * alpha * beta;

    const int ixL0 = ix - 1;
    const int iyT0 = iy - 1;
    int R[5];
#pragma unroll
    for (int j = 0; j < 5; ++j) R[j] = min(max(iyT0 + j, 0), HH - 1);

    const float* ib = inp + (size_t)(b * CC) * HW;

    f4 acc4[CC];
#pragma unroll
    for (int c = 0; c < CC; ++c) acc4[c] = (f4){0.f, 0.f, 0.f, 0.f};
    float accs[CC] = {0.f, 0.f, 0.f};

    const bool fast = (ixL0 >= 0) && (ixL0 <= WW - 5);
    if (fast) {
        const int a0 = ixL0 & ~3;   // aligned window start, a0+8 <= WW
        const int o  = ixL0 - a0;   // 0..3

        // ---- Issue ALL 30 patch loads before any consumption ----
        f4 P[30];
#pragma unroll
        for (int j = 0; j < 5; ++j) {
            const int ro = R[j] * WW + a0;
#pragma unroll
            for (int c = 0; c < CC; ++c) {
                const float* p = ib + (size_t)c * HW + ro;
                P[(j * 3 + c) * 2 + 0] = *(const f4*)(p);
                P[(j * 3 + c) * 2 + 1] = *(const f4*)(p + 4);
            }
        }

        // ---- Build 5x5 weight map (waits only on filter loads; the 30
        //      patch loads remain in flight under this VALU work) ----
        float Wm[5][5];
#pragma unroll
        for (int j = 0; j < 5; ++j)
#pragma unroll
            for (int i = 0; i < 5; ++i) Wm[j][i] = 0.0f;
#pragma unroll
        for (int dj = 0; dj < 4; ++dj) {
#pragma unroll
            for (int di = 0; di < 4; ++di) {
                const float f = ftv[dj * 4 + di];
                Wm[dj][di]         += f * wTL;
                Wm[dj][di + 1]     += f * wTR;
                Wm[dj + 1][di]     += f * wBL;
                Wm[dj + 1][di + 1] += f * wBR;
            }
        }

        // ---- Barrel-shift weight rows into two f4 windows per row ----
        const bool s2 = (o & 2) != 0;
        const bool s1 = (o & 1) != 0;
        f4 WL[5], WH[5];
#pragma unroll
        for (int j = 0; j < 5; ++j) {
            float t[8];
#pragma unroll
            for (int i = 0; i < 8; ++i) t[i] = (i < 5) ? Wm[j][i] : 0.0f;
            float u[8];
#pragma unroll
            for (int i = 0; i < 8; ++i)
                u[i] = s2 ? ((i >= 2) ? t[i - 2] : 0.0f) : t[i];
            float w[8];
#pragma unroll
            for (int i = 0; i < 8; ++i)
                w[i] = s1 ? ((i >= 1) ? u[i - 1] : 0.0f) : u[i];
            WL[j] = (f4){w[0], w[1], w[2], w[3]};
            WH[j] = (f4){w[4], w[5], w[6], w[7]};
        }

        // ---- Consume: 30 f4 FMAs (packed-f32 capable) ----
#pragma unroll
        for (int j = 0; j < 5; ++j) {
#pragma unroll
            for (int c = 0; c < CC; ++c) {
                acc4[c] += P[(j * 3 + c) * 2 + 0] * WL[j];
                acc4[c] += P[(j * 3 + c) * 2 + 1] * WH[j];
            }
        }
    } else {
        // ---- Rare slow path (window crosses horizontal border) ----
        float Wm[5][5];
#pragma unroll
        for (int j = 0; j < 5; ++j)
#pragma unroll
            for (int i = 0; i < 5; ++i) Wm[j][i] = 0.0f;
#pragma unroll
        for (int dj = 0; dj < 4; ++dj) {
#pragma unroll
            for (int di = 0; di < 4; ++di) {
                const float f = ftv[dj * 4 + di];
                Wm[dj][di]         += f * wTL;
                Wm[dj][di + 1]     += f * wTR;
                Wm[dj + 1][di]     += f * wBL;
                Wm[dj + 1][di + 1] += f * wBR;
            }
        }
        int S[5];
#pragma unroll
        for (int i = 0; i < 5; ++i) S[i] = min(max(ixL0 + i, 0), WW - 1);
#pragma unroll
        for (int c = 0; c < CC; ++c) {
            const float* ic = ib + (size_t)c * HW;
            float a = 0.0f;
#pragma unroll
            for (int j = 0; j < 5; ++j) {
                const float* row = ic + (size_t)R[j] * WW;
#pragma unroll
                for (int i = 0; i < 5; ++i) a += row[S[i]] * Wm[j][i];
            }
            accs[c] = a;
        }
    }

    // ---- Coalesced stores (per-lane horizontal reduce of f4 acc) ----
    float* ob = out + (size_t)(b * CC) * HW + rem;
#pragma unroll
    for (int c = 0; c < CC; ++c) {
        ob[(size_t)c * HW] =
            acc4[c][0] + acc4[c][1] + acc4[c][2] + acc4[c][3] + accs[c];
    }
}

extern "C" void kernel_launch(void* const* d_in, const int* in_sizes, int n_in,
                              void* d_out, int out_size, void* d_ws, size_t ws_size,
                              hipStream_t stream) {
    const float* teninput  = (const float*)d_in[0];
    const float* tenflow   = (const float*)d_in[1];
    const float* tenfilter = (const float*)d_in[2];
    float* out = (float*)d_out;

    const int blocks = (BB * HW) / 256;  // 7680
    filter_interp_batch<<<blocks, 256, 0, stream>>>(teninput, tenflow, tenfilter, out);
}